// Round 13
// baseline (159.873 us; speedup 1.0000x reference)
//
#include <hip/hip_runtime.h>
#include <math.h>
#include <stdint.h>

#define PI2 6.28318530717958647692f

typedef __bf16 bf16x8 __attribute__((ext_vector_type(8)));
typedef float f32x4 __attribute__((ext_vector_type(4)));

typedef __attribute__((address_space(1))) const void gvoid_t;
typedef __attribute__((address_space(3))) void lvoid_t;

__device__ __forceinline__ void g2l16(const void* g, void* l) {
    __builtin_amdgcn_global_load_lds(
        reinterpret_cast<gvoid_t*>(reinterpret_cast<uintptr_t>(g)),
        reinterpret_cast<lvoid_t*>(reinterpret_cast<uintptr_t>(l)),
        16, 0, 0);
}

__device__ __forceinline__ short f2bf(float f) {
    unsigned u = __float_as_uint(f);
    u += 0x7FFFu + ((u >> 16) & 1u);          // round-to-nearest-even
    return (short)(u >> 16);
}

__device__ __forceinline__ unsigned pack2bf(float a, float b) {
    return (unsigned)(unsigned short)f2bf(a) |
           ((unsigned)(unsigned short)f2bf(b) << 16);
}

__device__ __forceinline__ float bflo(unsigned v) { return __uint_as_float(v << 16); }
__device__ __forceinline__ float bfhi(unsigned v) { return __uint_as_float(v & 0xFFFF0000u); }

// XCD-locality swizzle (G must be a multiple of 8 -> bijective).
__device__ __forceinline__ int xcd_swizzle(int blk, int G) {
    return (blk & 7) * (G >> 3) + (blk >> 3);
}

// ---------------------------------------------------------------------------
// Fused aux kernel, block-range dispatch, 5120 blocks (R12-proven):
//   [0,   512):  x double radix-2 fold: xee/xeo (1024x1024), xo (1024x2048)
//   [512, 1024): B1e (1024x1024) even-freq basis split by r-parity
//   [1024,2048): B1o (1024x2048) odd-freq basis
//   [2048,2560): VSe/VSo via LDS transpose + S-mul + k-fold
//   [2560,3072): B2' (1024x1024), frequency-parity row groups
//   [3072,5120): Ucat (4096x1024) permuted to B2' row order
// ---------------------------------------------------------------------------
__global__ __launch_bounds__(256) void aux_all8(
    const float* __restrict__ x,
    const float* __restrict__ Ur, const float* __restrict__ Ui,
    const float* __restrict__ S,
    const float* __restrict__ Vr, const float* __restrict__ Vi,
    short* __restrict__ xee, short* __restrict__ xeo, short* __restrict__ xo,
    short* __restrict__ B1e, short* __restrict__ B1o,
    short* __restrict__ VSe, short* __restrict__ VSo,
    short* __restrict__ B2, short* __restrict__ Ucat)
{
    __shared__ float tlds0[64][68];
    __shared__ float tlds1[64][68];
    __shared__ float s_lo[64], s_hi[64];
    const int b   = (int)blockIdx.x;
    const int tid = threadIdx.x;

    if (b < 512) {
        // double fold: xee=(x0+x2)+(x1+x3), xeo=(x0+x2)-(x1+x3),
        //              xo[j]=x0-x2, xo[j+1024]=x1-x3  (xq = x[:, q*1024+j])
        unsigned i = (b * 256u + tid) * 8u;       // 1M positions
        int r = i >> 10, j0 = i & 1023;
        const float* xr = x + (size_t)r * 4096 + j0;
        float4 p0 = ((const float4*)xr)[0],        p1 = ((const float4*)xr)[1];
        float4 q0 = ((const float4*)(xr + 1024))[0], q1 = ((const float4*)(xr + 1024))[1];
        float4 s0 = ((const float4*)(xr + 2048))[0], s1 = ((const float4*)(xr + 2048))[1];
        float4 t0 = ((const float4*)(xr + 3072))[0], t1 = ((const float4*)(xr + 3072))[1];
        float el[8] = {p0.x + s0.x, p0.y + s0.y, p0.z + s0.z, p0.w + s0.w,
                       p1.x + s1.x, p1.y + s1.y, p1.z + s1.z, p1.w + s1.w};
        float eh[8] = {q0.x + t0.x, q0.y + t0.y, q0.z + t0.z, q0.w + t0.w,
                       q1.x + t1.x, q1.y + t1.y, q1.z + t1.z, q1.w + t1.w};
        float ol[8] = {p0.x - s0.x, p0.y - s0.y, p0.z - s0.z, p0.w - s0.w,
                       p1.x - s1.x, p1.y - s1.y, p1.z - s1.z, p1.w - s1.w};
        float oh[8] = {q0.x - t0.x, q0.y - t0.y, q0.z - t0.z, q0.w - t0.w,
                       q1.x - t1.x, q1.y - t1.y, q1.z - t1.z, q1.w - t1.w};
        size_t base1k = (size_t)r * 1024 + j0;
        uint4 oee = {pack2bf(el[0] + eh[0], el[1] + eh[1]),
                     pack2bf(el[2] + eh[2], el[3] + eh[3]),
                     pack2bf(el[4] + eh[4], el[5] + eh[5]),
                     pack2bf(el[6] + eh[6], el[7] + eh[7])};
        *(uint4*)(xee + base1k) = oee;
        uint4 oeo = {pack2bf(el[0] - eh[0], el[1] - eh[1]),
                     pack2bf(el[2] - eh[2], el[3] - eh[3]),
                     pack2bf(el[4] - eh[4], el[5] - eh[5]),
                     pack2bf(el[6] - eh[6], el[7] - eh[7])};
        *(uint4*)(xeo + base1k) = oeo;
        size_t base2k = (size_t)r * 2048 + j0;
        uint4 olo = {pack2bf(ol[0], ol[1]), pack2bf(ol[2], ol[3]),
                     pack2bf(ol[4], ol[5]), pack2bf(ol[6], ol[7])};
        *(uint4*)(xo + base2k) = olo;
        uint4 ohi = {pack2bf(oh[0], oh[1]), pack2bf(oh[2], oh[3]),
                     pack2bf(oh[4], oh[5]), pack2bf(oh[6], oh[7])};
        *(uint4*)(xo + base2k + 1024) = ohi;
    } else if (b < 1024) {
        // B1e (1024x1024)
        unsigned i = ((b - 512) * 256u + tid) * 8u;
        int p = i >> 10, j0 = i & 1023;
        const float inv_n = 1.0f / 4096.0f;
        float v[8];
        if (p < 256) {
            if (p == 0) {
                #pragma unroll
                for (int u = 0; u < 8; ++u) v[u] = inv_n;
            } else {
                #pragma unroll
                for (int u = 0; u < 8; ++u) {
                    int t = (p * (j0 + u)) & 1023;           // cos F=4a
                    v[u] = 2.0f * inv_n * cosf((float)t * (PI2 / 1024.0f));
                }
            }
        } else if (p < 512) {
            int a = p - 256;
            #pragma unroll
            for (int u = 0; u < 8; ++u) {
                int t = (a * (j0 + u)) & 1023;               // -sin F=4a
                v[u] = -2.0f * inv_n * sinf((float)t * (PI2 / 1024.0f));
            }
        } else if (p < 768) {
            int q = 2 * (p - 512) + 1;
            #pragma unroll
            for (int u = 0; u < 8; ++u) {
                int t = (q * (j0 + u)) & 2047;               // cos F=4a+2
                v[u] = 2.0f * inv_n * cosf((float)t * (PI2 / 2048.0f));
            }
        } else {
            int q = 2 * (p - 768) + 1;
            #pragma unroll
            for (int u = 0; u < 8; ++u) {
                int t = (q * (j0 + u)) & 2047;               // -sin F=4a+2
                v[u] = -2.0f * inv_n * sinf((float)t * (PI2 / 2048.0f));
            }
        }
        uint4 o = {pack2bf(v[0], v[1]), pack2bf(v[2], v[3]),
                   pack2bf(v[4], v[5]), pack2bf(v[6], v[7])};
        *(uint4*)(B1e + i) = o;
    } else if (b < 2048) {
        // B1o (1024x2048): odd-freq basis over j<2048
        unsigned i = ((b - 1024) * 256u + tid) * 8u;
        int p = i >> 11, j0 = i & 2047;
        const float inv_n = 1.0f / 4096.0f;
        float v[8];
        if (p < 512) {
            int c = 2 * p + 1;
            #pragma unroll
            for (int u = 0; u < 8; ++u) {
                int t = (c * (j0 + u)) & 4095;
                v[u] = 2.0f * inv_n * cosf((float)t * (PI2 / 4096.0f));
            }
        } else {
            int m = 2 * (p - 512) + 1;
            #pragma unroll
            for (int u = 0; u < 8; ++u) {
                int t = (m * (j0 + u)) & 4095;
                v[u] = -2.0f * inv_n * sinf((float)t * (PI2 / 4096.0f));
            }
        }
        uint4 o = {pack2bf(v[0], v[1]), pack2bf(v[2], v[3]),
                   pack2bf(v[4], v[5]), pack2bf(v[6], v[7])};
        *(uint4*)(B1o + i) = o;
    } else if (b < 2560) {
        // LDS-tiled V transpose + S-mul + k-fold. 256 blocks per matrix.
        const int bb  = b - 2048;
        const int m   = bb >> 8;           // 0 = Vr, 1 = Vi
        const int tt  = bb & 255;
        const int tkk = tt >> 4;           // 0..15 -> k rows tkk*64, +1024
        const int tc  = tt & 15;
        const float* srcA = (m ? Vi : Vr) + (size_t)(tkk * 64) * 1024 + tc * 64;
        const float* srcB = srcA + (size_t)1024 * 1024;   // k + 1024

        #pragma unroll
        for (int pass = 0; pass < 4; ++pass) {
            int r  = pass * 16 + (tid >> 4);        // 0..63
            int cq = (tid & 15) * 4;                // 0..60
            *(float4*)&tlds0[r][cq] = *(const float4*)(srcA + (size_t)r * 1024 + cq);
            *(float4*)&tlds1[r][cq] = *(const float4*)(srcB + (size_t)r * 1024 + cq);
        }
        if (tid < 64) {
            s_lo[tid] = S[tkk * 64 + tid];
            s_hi[tid] = S[tkk * 64 + tid + 1024];
        }
        __syncthreads();

        const int cl = tid & 63;                    // local col -> f row
        const int ch = (tid >> 6) * 16;             // k chunk
        const int c  = tc * 64 + cl;
        int f;
        if (c & 1) {
            f = 1024 + (m << 9) + (c >> 1);
        } else {
            int r2 = c >> 1;
            f = ((r2 & 1) << 9) + (m << 8) + (r2 >> 1);
        }
        float ve[16], vo[16];
        #pragma unroll
        for (int j = 0; j < 16; ++j) {
            float a   = tlds0[ch + j][cl] * s_lo[ch + j];
            float bb2 = tlds1[ch + j][cl] * s_hi[ch + j];
            ve[j] = a + bb2;
            vo[j] = a - bb2;
        }
        uint4* de = (uint4*)(VSe + (size_t)f * 1024 + tkk * 64 + ch);
        de[0] = (uint4){pack2bf(ve[0],  ve[1]),  pack2bf(ve[2],  ve[3]),
                        pack2bf(ve[4],  ve[5]),  pack2bf(ve[6],  ve[7])};
        de[1] = (uint4){pack2bf(ve[8],  ve[9]),  pack2bf(ve[10], ve[11]),
                        pack2bf(ve[12], ve[13]), pack2bf(ve[14], ve[15])};
        uint4* dox = (uint4*)(VSo + (size_t)f * 1024 + tkk * 64 + ch);
        dox[0] = (uint4){pack2bf(vo[0],  vo[1]),  pack2bf(vo[2],  vo[3]),
                         pack2bf(vo[4],  vo[5]),  pack2bf(vo[6],  vo[7])};
        dox[1] = (uint4){pack2bf(vo[8],  vo[9]),  pack2bf(vo[10], vo[11]),
                         pack2bf(vo[12], vo[13]), pack2bf(vo[14], vo[15])};
    } else if (b < 3072) {
        // B2' (1024x1024), parity-grouped rows, no S
        unsigned i = ((b - 2560) * 256u + tid) * 8u;
        int p = i >> 10, k0 = i & 1023;
        int grp = p >> 8, pp = p & 255;
        const float inv_n = 1.0f / 2048.0f;
        float v[8];
        if (grp == 0) {
            if (p == 0) {
                #pragma unroll
                for (int u = 0; u < 8; ++u) v[u] = inv_n;
            } else {
                #pragma unroll
                for (int u = 0; u < 8; ++u) {
                    int t = (pp * (k0 + u)) & 1023;      // cos F=2pp
                    v[u] = 2.0f * inv_n * cosf((float)t * (PI2 / 1024.0f));
                }
            }
        } else if (grp == 1) {
            #pragma unroll
            for (int u = 0; u < 8; ++u) {
                int t = (pp * (k0 + u)) & 1023;          // sin F=2pp
                v[u] = -2.0f * inv_n * sinf((float)t * (PI2 / 1024.0f));
            }
        } else if (grp == 2) {
            int q = 2 * pp + 1;
            #pragma unroll
            for (int u = 0; u < 8; ++u) {
                int t = (q * (k0 + u)) & 2047;           // cos F=2pp+1
                v[u] = 2.0f * inv_n * cosf((float)t * (PI2 / 2048.0f));
            }
        } else {
            int q = 2 * pp + 1;
            #pragma unroll
            for (int u = 0; u < 8; ++u) {
                int t = (q * (k0 + u)) & 2047;           // sin F=2pp+1
                v[u] = -2.0f * inv_n * sinf((float)t * (PI2 / 2048.0f));
            }
        }
        uint4 o = {pack2bf(v[0], v[1]), pack2bf(v[2], v[3]),
                   pack2bf(v[4], v[5]), pack2bf(v[6], v[7])};
        *(uint4*)(B2 + i) = o;
    } else {
        // Ucat (4096x1024), columns permuted to B2' row order.
        unsigned i = ((b - 3072) * 256u + tid) * 8u;
        int o_ = i >> 10, c = i & 1023;
        int grp = c >> 8, cc = c & 255;
        int par = grp >> 1;
        const float2* s2 = (const float2*)(((grp & 1) ? Ui : Ur)
                                           + (size_t)o_ * 512 + 2 * cc);
        float v[8];
        #pragma unroll
        for (int j = 0; j < 8; ++j) {
            float2 q = s2[j];
            v[j] = par ? q.y : q.x;
        }
        uint4 o = {pack2bf(v[0], v[1]), pack2bf(v[2], v[3]),
                   pack2bf(v[4], v[5]), pack2bf(v[6], v[7])};
        *(uint4*)(Ucat + i) = o;
    }
}

// ---------------------------------------------------------------------------
// 128x128 MFMA tile core, BK=64, XOR-swizzled LDS, double-buffered
// (round-5 proven). LDS 64 KB/block -> 2 blocks/CU.
// ---------------------------------------------------------------------------
__device__ __forceinline__ void tile_core(
    const short* __restrict__ A, int lda,
    const short* __restrict__ B, int ldb, int K,
    short* As, short* Bs, int bm, int bn, f32x4 (&acc)[4][4])
{
    const int tid  = threadIdx.x;
    const int wave = tid >> 6;
    const int lane = tid & 63;
    const int wm   = (wave >> 1) << 6;
    const int wn   = (wave & 1) << 6;
    const int l16  = lane & 15;
    const int quad = lane >> 4;
    const int rk   = l16 & 7;

    int aoff[4], boff[4], loff[4];
    #pragma unroll
    for (int p = 0; p < 4; ++p) {
        int L   = p * 256 + wave * 64 + lane;
        int row = L >> 3;
        int swz = (L & 7) ^ (row & 7);
        aoff[p] = (bm + row) * lda + swz * 8;
        boff[p] = (bn + row) * ldb + swz * 8;
        loff[p] = L * 8;
    }

    // prologue: stage K-tile 0 into buffer 0
    #pragma unroll
    for (int p = 0; p < 4; ++p) g2l16(A + aoff[p], As + loff[p]);
    #pragma unroll
    for (int p = 0; p < 4; ++p) g2l16(B + boff[p], Bs + loff[p]);
    __syncthreads();

    int cur = 0;
    for (int k0 = 0; k0 < K; k0 += 64) {
        const int nxt = cur ^ 1;
        if (k0 + 64 < K) {
            #pragma unroll
            for (int p = 0; p < 4; ++p)
                g2l16(A + aoff[p] + k0 + 64, As + nxt * 8192 + loff[p]);
            #pragma unroll
            for (int p = 0; p < 4; ++p)
                g2l16(B + boff[p] + k0 + 64, Bs + nxt * 8192 + loff[p]);
        }

        const short* Asc = As + cur * 8192;
        const short* Bsc = Bs + cur * 8192;
        #pragma unroll
        for (int h = 0; h < 2; ++h) {
            const int cs8 = ((((h << 2) | quad) ^ rk) << 3);
            bf16x8 b[4];
            #pragma unroll
            for (int nt = 0; nt < 4; ++nt)
                b[nt] = *(const bf16x8*)(Bsc + (wn + nt * 16 + l16) * 64 + cs8);
            #pragma unroll
            for (int mt = 0; mt < 4; ++mt) {
                bf16x8 a = *(const bf16x8*)(Asc + (wm + mt * 16 + l16) * 64 + cs8);
                #pragma unroll
                for (int nt = 0; nt < 4; ++nt)
                    acc[mt][nt] = __builtin_amdgcn_mfma_f32_16x16x32_bf16(
                        a, b[nt], acc[mt][nt], 0, 0, 0);
            }
        }
        __syncthreads();
        cur = nxt;
    }
}

// ---------------------------------------------------------------------------
// 64x128 MFMA tile core, BK=64, XOR-swizzled LDS, double-buffered (R7-proven
// fragment geometry). LDS 48 KB/block. Waves 2x2; each wave 32x64.
// ---------------------------------------------------------------------------
__device__ __forceinline__ void tile_core64(
    const short* __restrict__ A, int lda,
    const short* __restrict__ B, int ldb, int K,
    short* As, short* Bs, int bm, int bn, f32x4 (&acc)[2][4])
{
    const int tid  = threadIdx.x;
    const int wave = tid >> 6;
    const int lane = tid & 63;
    const int wm   = (wave >> 1) << 5;   // 0 or 32
    const int wn   = (wave & 1) << 6;    // 0 or 64
    const int l16  = lane & 15;
    const int quad = lane >> 4;
    const int rk   = l16 & 7;

    int aoff[2], boff[4], la[2], lb[4];
    #pragma unroll
    for (int p = 0; p < 2; ++p) {
        int L   = p * 256 + tid;
        int row = L >> 3;
        int swz = (L & 7) ^ (row & 7);
        aoff[p] = (bm + row) * lda + swz * 8;
        la[p]   = L * 8;
    }
    #pragma unroll
    for (int p = 0; p < 4; ++p) {
        int L   = p * 256 + tid;
        int row = L >> 3;
        int swz = (L & 7) ^ (row & 7);
        boff[p] = (bn + row) * ldb + swz * 8;
        lb[p]   = L * 8;
    }

    #pragma unroll
    for (int p = 0; p < 2; ++p) g2l16(A + aoff[p], As + la[p]);
    #pragma unroll
    for (int p = 0; p < 4; ++p) g2l16(B + boff[p], Bs + lb[p]);
    __syncthreads();

    int cur = 0;
    for (int k0 = 0; k0 < K; k0 += 64) {
        const int nxt = cur ^ 1;
        if (k0 + 64 < K) {
            #pragma unroll
            for (int p = 0; p < 2; ++p)
                g2l16(A + aoff[p] + k0 + 64, As + nxt * 4096 + la[p]);
            #pragma unroll
            for (int p = 0; p < 4; ++p)
                g2l16(B + boff[p] + k0 + 64, Bs + nxt * 8192 + lb[p]);
        }

        const short* Asc = As + cur * 4096;
        const short* Bsc = Bs + cur * 8192;
        #pragma unroll
        for (int h = 0; h < 2; ++h) {
            const int cs8 = ((((h << 2) | quad) ^ rk) << 3);
            bf16x8 b[4];
            #pragma unroll
            for (int nt = 0; nt < 4; ++nt)
                b[nt] = *(const bf16x8*)(Bsc + (wn + nt * 16 + l16) * 64 + cs8);
            #pragma unroll
            for (int mt = 0; mt < 2; ++mt) {
                bf16x8 a = *(const bf16x8*)(Asc + (wm + mt * 16 + l16) * 64 + cs8);
                #pragma unroll
                for (int nt = 0; nt < 4; ++nt)
                    acc[mt][nt] = __builtin_amdgcn_mfma_f32_16x16x32_bf16(
                        a, b[nt], acc[mt][nt], 0, 0, 0);
            }
        }
        __syncthreads();
        cur = nxt;
    }
}

__device__ __forceinline__ void store_tile_bf16(
    f32x4 (&acc)[4][4], short* __restrict__ C, int ldc, int bm, int bn)
{
    const int tid  = threadIdx.x;
    const int wave = tid >> 6;
    const int lane = tid & 63;
    const int wm   = (wave >> 1) << 6;
    const int wn   = (wave & 1) << 6;
    const int l16  = lane & 15;
    const int quad = lane >> 4;
    #pragma unroll
    for (int nt = 0; nt < 4; ++nt) {
        int col = bn + wn + nt * 16 + l16;
        #pragma unroll
        for (int mt = 0; mt < 4; ++mt) {
            int rowb = bm + wm + mt * 16 + quad * 4;
            #pragma unroll
            for (int r = 0; r < 4; ++r)
                C[(size_t)(rowb + r) * ldc + col] = f2bf(acc[mt][nt][r]);
        }
    }
}

// Fragment-layout store: 8 coalesced uint4 per thread.
__device__ __forceinline__ void store_frag(
    f32x4 (&acc)[4][4], short* __restrict__ planeTile)
{
    uint4* p = (uint4*)planeTile;
    const int tid = threadIdx.x;
    #pragma unroll
    for (int c = 0; c < 8; ++c) {
        int nt = c >> 1, mt0 = (c & 1) * 2;
        uint4 o = {pack2bf(acc[mt0][nt][0],     acc[mt0][nt][1]),
                   pack2bf(acc[mt0][nt][2],     acc[mt0][nt][3]),
                   pack2bf(acc[mt0 + 1][nt][0], acc[mt0 + 1][nt][1]),
                   pack2bf(acc[mt0 + 1][nt][2], acc[mt0 + 1][nt][3])};
        p[c * 256 + tid] = o;
    }
}

// Reduce one fragment chunk (tile, c) across SK planes -> row-major output.
template <bool OUT_F32>
__device__ __forceinline__ void reduce_unit(
    const short* __restrict__ P, size_t planeU4, int SK,
    int tile, int c, int tilesX, void* __restrict__ Out, int ldc,
    const float* __restrict__ bias)
{
    const int bm = (tile / tilesX) << 7;
    const int bn = (tile % tilesX) << 7;
    const int tid  = threadIdx.x;
    const int wave = tid >> 6;
    const int lane = tid & 63;
    const int wm   = (wave >> 1) << 6;
    const int wn   = (wave & 1) << 6;
    const int l16  = lane & 15;
    const int quad = lane >> 4;
    const int nt   = c >> 1, mt0 = (c & 1) * 2;

    const uint4* P4 = (const uint4*)P;
    const size_t base = (size_t)tile * 2048 + (size_t)c * 256 + tid;
    float f[8] = {0, 0, 0, 0, 0, 0, 0, 0};
    for (int z = 0; z < SK; ++z) {
        uint4 v = P4[(size_t)z * planeU4 + base];
        f[0] += bflo(v.x); f[1] += bfhi(v.x);
        f[2] += bflo(v.y); f[3] += bfhi(v.y);
        f[4] += bflo(v.z); f[5] += bfhi(v.z);
        f[6] += bflo(v.w); f[7] += bfhi(v.w);
    }
    const int col = bn + wn + nt * 16 + l16;
    float bv = 0.f;
    if (OUT_F32) bv = bias[col];
    #pragma unroll
    for (int j = 0; j < 8; ++j) {
        int mt  = mt0 + (j >> 2);
        int row = bm + wm + mt * 16 + quad * 4 + (j & 3);
        if (OUT_F32)
            ((float*)Out)[(size_t)row * ldc + col] = f[j] + bv;
        else
            ((short*)Out)[(size_t)row * ldc + col] = f2bf(f[j]);
    }
}

// ---------------------------------------------------------------------------
// Merged dispatch, 1024 blocks (R12-proven):
//   [0,512):   folded stage-1 split-K GEMM (SK=4) -> s1 partial planes.
//     tile tx<4:  Xp cols [0,512)    = xee @ B1e[0:512]^T    (Kpart=256)
//     tile tx<8:  Xp cols [512,1024) = xeo @ B1e[512:1024]^T (Kpart=256)
//     tile tx>=8: Xp cols [1024,2048)= xo  @ B1o^T           (Kpart=512)
//   [512,1024): W2 = B2' @ VS?^T (K=1024 after k-fold; SK=4, Kpart=256).
// ---------------------------------------------------------------------------
__global__ __launch_bounds__(256, 2) void gemm_s1w2(
    const short* __restrict__ xee, const short* __restrict__ xeo,
    const short* __restrict__ xo,
    const short* __restrict__ B1e, const short* __restrict__ B1o,
    const short* __restrict__ B2,
    const short* __restrict__ VSe, const short* __restrict__ VSo,
    short* __restrict__ P, short* __restrict__ PW)
{
    __shared__ __align__(16) short As[2 * 128 * 64];
    __shared__ __align__(16) short Bs[2 * 128 * 64];

    f32x4 acc[4][4];
    #pragma unroll
    for (int i = 0; i < 4; ++i)
        #pragma unroll
        for (int j = 0; j < 4; ++j)
            acc[i][j] = (f32x4){0.f, 0.f, 0.f, 0.f};

    const int raw = (int)blockIdx.x;
    if (raw < 512) {
        const int u    = xcd_swizzle(raw, 512);
        const int z    = u >> 7;          // SK = 4
        const int tile = u & 127;         // 8 x 16 tiles
        const int tx   = tile & 15, ty = tile >> 4;
        const int bm   = ty << 7;
        if (tx < 8) {
            // even-freq half: K=1024, Kpart=256
            const short* A = ((tx & 4) ? xeo : xee) + (size_t)z * 256;
            const short* B = B1e + (size_t)z * 256;
            tile_core(A, 1024, B, 1024, 256, As, Bs, bm, tx << 7, acc);
        } else {
            // odd-freq half: K=2048, Kpart=512
            const short* A = xo + (size_t)z * 512;
            const short* B = B1o + (size_t)z * 512;
            tile_core(A, 2048, B, 2048, 512, As, Bs, bm, (tx & 7) << 7, acc);
        }
        store_frag(acc, P + (size_t)z * 2097152 + (size_t)tile * 16384);
    } else {
        const int u    = xcd_swizzle(raw - 512, 512);
        const int z    = u >> 7;          // SK = 4, Kpart = 256
        const int tile = u & 127;         // 8(p) x 16(f) tiles
        const int bm   = (tile >> 4) << 7;
        const int bn   = (tile & 15) << 7;
        const short* Bv = (bm < 512) ? VSe : VSo;   // freq-parity group

        tile_core(B2 + (size_t)z * 256, 1024, Bv + (size_t)z * 256, 1024,
                  256, As, Bs, bm, bn, acc);
        store_frag(acc, PW + (size_t)z * 2097152 + (size_t)tile * 16384);
    }
}

// Merged reduce: blocks [0,1024) -> Xp from P; [1024,2048) -> W2 from PW.
__global__ __launch_bounds__(256) void reduce_s1w2(
    const short* __restrict__ P, const short* __restrict__ PW,
    short* __restrict__ Xp, short* __restrict__ W2)
{
    const int b   = (int)blockIdx.x;
    const int sub = b & 1023;
    if (b < 1024)
        reduce_unit<false>(P,  (size_t)2097152 >> 3, 4, sub >> 3, sub & 7,
                           16, Xp, 2048, nullptr);
    else
        reduce_unit<false>(PW, (size_t)2097152 >> 3, 4, sub >> 3, sub & 7,
                           16, W2, 2048, nullptr);
}

// ---------------------------------------------------------------------------
// Generic split-K GEMM into fragment-layout bf16 partial planes.
// ---------------------------------------------------------------------------
__global__ __launch_bounds__(256, 2) void gemm_sk_frag(
    const short* __restrict__ A, int lda,
    const short* __restrict__ B, int ldb,
    short* __restrict__ P, size_t planeShorts, int Kpart,
    int tileShift, int tilesXShift)
{
    __shared__ __align__(16) short As[2 * 128 * 64];
    __shared__ __align__(16) short Bs[2 * 128 * 64];

    f32x4 acc[4][4];
    #pragma unroll
    for (int i = 0; i < 4; ++i)
        #pragma unroll
        for (int j = 0; j < 4; ++j)
            acc[i][j] = (f32x4){0.f, 0.f, 0.f, 0.f};

    const int u    = xcd_swizzle((int)blockIdx.x, (int)gridDim.x);
    const int z    = u >> tileShift;
    const int tile = u & ((1 << tileShift) - 1);
    const int bm   = (tile >> tilesXShift) << 7;
    const int bn   = (tile & ((1 << tilesXShift) - 1)) << 7;

    tile_core(A + (size_t)z * Kpart, lda, B + (size_t)z * Kpart, ldb, Kpart,
              As, Bs, bm, bn, acc);
    store_frag(acc, P + (size_t)z * planeShorts + (size_t)tile * 16384);
}

template <bool OUT_F32>
__global__ __launch_bounds__(256) void reduce_frag(
    const short* __restrict__ P, size_t planeShorts, int SK,
    int tilesX, void* __restrict__ Out, int ldc,
    const float* __restrict__ bias)
{
    reduce_unit<OUT_F32>(P, planeShorts >> 3, SK,
                         (int)(blockIdx.x >> 3), (int)(blockIdx.x & 7),
                         tilesX, Out, ldc, bias);
}

// ---------------------------------------------------------------------------
// Final out stage, 64x128 tiles: out = G @ Ucat^T + bias (1024x4096, K=1024).
// 512 blocks (16 m-tiles x 32 n-tiles) = 2 blocks/CU vs 1/CU at 128x128 --
// halves the serial K-chain exposure of the former 256-block direct form.
// ---------------------------------------------------------------------------
__global__ __launch_bounds__(256, 2) void gemm_out64(
    const short* __restrict__ Gm, const short* __restrict__ Ucat,
    float* __restrict__ out, const float* __restrict__ bias)
{
    __shared__ __align__(16) short As[2 * 64 * 64];
    __shared__ __align__(16) short Bs[2 * 128 * 64];

    f32x4 acc[2][4];
    #pragma unroll
    for (int i = 0; i < 2; ++i)
        #pragma unroll
        for (int j = 0; j < 4; ++j)
            acc[i][j] = (f32x4){0.f, 0.f, 0.f, 0.f};

    const int u  = xcd_swizzle((int)blockIdx.x, 512);
    const int bm = (u >> 5) << 6;    // 16 m-tiles of 64
    const int bn = (u & 31) << 7;    // 32 n-tiles of 128

    tile_core64(Gm, 1024, Ucat, 1024, 1024, As, Bs, bm, bn, acc);

    const int tid  = threadIdx.x;
    const int wave = tid >> 6;
    const int lane = tid & 63;
    const int wm   = (wave >> 1) << 5;
    const int wn   = (wave & 1) << 6;
    const int l16  = lane & 15;
    const int quad = lane >> 4;

    #pragma unroll
    for (int nt = 0; nt < 4; ++nt) {
        int col = bn + wn + nt * 16 + l16;
        float bv = bias[col];
        #pragma unroll
        for (int mt = 0; mt < 2; ++mt) {
            int rowb = bm + wm + mt * 16 + quad * 4;
            #pragma unroll
            for (int r = 0; r < 4; ++r)
                out[(size_t)(rowb + r) * 4096 + col] = acc[mt][nt][r] + bv;
        }
    }
}

// ---------------------------------------------------------------------------
// Direct GEMM (full K): fallback path.
// ---------------------------------------------------------------------------
template <bool OUT_F32>
__global__ __launch_bounds__(256, 2) void gemm_direct(
    const short* __restrict__ A, int lda,
    const short* __restrict__ B, int ldb,
    void* __restrict__ Cv, int ldc,
    const float* __restrict__ bias, int K)
{
    __shared__ __align__(16) short As[2 * 128 * 64];
    __shared__ __align__(16) short Bs[2 * 128 * 64];

    f32x4 acc[4][4];
    #pragma unroll
    for (int i = 0; i < 4; ++i)
        #pragma unroll
        for (int j = 0; j < 4; ++j)
            acc[i][j] = (f32x4){0.f, 0.f, 0.f, 0.f};

    const int bm = blockIdx.y << 7;
    const int bn = blockIdx.x << 7;
    tile_core(A, lda, B, ldb, K, As, Bs, bm, bn, acc);

    const int tid  = threadIdx.x;
    const int wave = tid >> 6;
    const int lane = tid & 63;
    const int wm   = (wave >> 1) << 6;
    const int wn   = (wave & 1) << 6;
    const int l16  = lane & 15;
    const int quad = lane >> 4;

    if (OUT_F32) {
        float* C = (float*)Cv;
        #pragma unroll
        for (int nt = 0; nt < 4; ++nt) {
            int col = bn + wn + nt * 16 + l16;
            float bv = bias ? bias[col] : 0.f;
            #pragma unroll
            for (int mt = 0; mt < 4; ++mt) {
                int rowb = bm + wm + mt * 16 + quad * 4;
                #pragma unroll
                for (int r = 0; r < 4; ++r)
                    C[(size_t)(rowb + r) * ldc + col] = acc[mt][nt][r] + bv;
            }
        }
    } else {
        store_tile_bf16(acc, (short*)Cv, ldc, bm, bn);
    }
}

extern "C" void kernel_launch(void* const* d_in, const int* in_sizes, int n_in,
                              void* d_out, int out_size, void* d_ws, size_t ws_size,
                              hipStream_t stream) {
    const float* x    = (const float*)d_in[0];
    const float* Ur   = (const float*)d_in[1];
    const float* Ui   = (const float*)d_in[2];
    const float* S    = (const float*)d_in[3];
    const float* Vr   = (const float*)d_in[4];
    const float* Vi   = (const float*)d_in[5];
    const float* bias = (const float*)d_in[6];
    float* out = (float*)d_out;

    short* ws    = (short*)d_ws;
    short* xee   = ws;                                  // 1024*1024
    short* xeo   = xee   + (size_t)1024 * 1024;         // 1024*1024
    short* xo    = xeo   + (size_t)1024 * 1024;         // 1024*2048
    short* B1e   = xo    + (size_t)1024 * 2048;         // 1024*1024
    short* B1o   = B1e   + (size_t)1024 * 1024;         // 1024*2048
    short* VSe   = B1o   + (size_t)1024 * 2048;         // 2048*1024
    short* VSo   = VSe   + (size_t)2048 * 1024;         // 2048*1024
    short* B2    = VSo   + (size_t)2048 * 1024;         // 1024*1024
    short* Ucat  = B2    + (size_t)1024 * 1024;         // 4096*1024
    short* Xp    = Ucat  + (size_t)4096 * 1024;         // 1024*2048
    short* W2    = Xp    + (size_t)1024 * 2048;         // 1024*2048
    short* Gm    = W2    + (size_t)1024 * 2048;         // 1024*1024
    short* Pp    = Gm    + (size_t)1024 * 1024;         // partials 8.39M shorts
    short* PW    = Pp    + (size_t)8388608;             // W2 partials 8.39M

    const size_t need = (size_t)((char*)(PW + (size_t)8388608) - (char*)d_ws);

    aux_all8<<<dim3(5120), 256, 0, stream>>>(
        x, Ur, Ui, S, Vr, Vi, xee, xeo, xo, B1e, B1o, VSe, VSo, B2, Ucat);

    if (ws_size >= need) {
        // [s1 || W2] merged (1024 blocks, both SK=4)
        gemm_s1w2<<<dim3(1024), 256, 0, stream>>>(
            xee, xeo, xo, B1e, B1o, B2, VSe, VSo, Pp, PW);
        reduce_s1w2<<<dim3(2048), 256, 0, stream>>>(Pp, PW, Xp, W2);

        // G = Xp @ W2^T (1024x1024, K=2048; SK=8, Kpart=256, 512 blocks)
        gemm_sk_frag<<<dim3(512), 256, 0, stream>>>(
            Xp, 2048, W2, 2048, Pp, (size_t)1048576, 256, 6, 3);
        reduce_frag<false><<<dim3(512), 256, 0, stream>>>(
            Pp, (size_t)1048576, 8, 8, Gm, 1024, nullptr);

        // out = G @ Ucat^T + bias (1024x4096, K=1024) -- 64x128 tiles,
        // 512 blocks = 2/CU (vs 1/CU at 128x128 in R11/R12).
        gemm_out64<<<dim3(512), 256, 0, stream>>>(Gm, Ucat, out, bias);
    } else {
        // Fallback: direct GEMMs, pointer-offset outputs for s1 thirds.
        gemm_direct<false><<<dim3(4, 8), 256, 0, stream>>>(
            xee, 1024, B1e, 1024, Xp, 2048, nullptr, 1024);
        gemm_direct<false><<<dim3(4, 8), 256, 0, stream>>>(
            xeo, 1024, B1e + (size_t)512 * 1024, 1024, Xp + 512, 2048,
            nullptr, 1024);
        gemm_direct<false><<<dim3(8, 8), 256, 0, stream>>>(
            xo, 2048, B1o, 2048, Xp + 1024, 2048, nullptr, 2048);
        gemm_direct<false><<<dim3(16, 4), 256, 0, stream>>>(
            B2, 1024, VSe, 1024, W2, 2048, nullptr, 1024);
        gemm_direct<false><<<dim3(16, 4), 256, 0, stream>>>(
            B2 + (size_t)512 * 1024, 1024, VSo, 1024,
            W2 + (size_t)512 * 2048, 2048, nullptr, 1024);
        gemm_direct<false><<<dim3(8, 8), 256, 0, stream>>>(
            Xp, 2048, W2, 2048, Gm, 1024, nullptr, 2048);
        gemm_direct<true><<<dim3(32, 8), 256, 0, stream>>>(
            Gm, 1024, Ucat, 1024, out, 4096, bias, 1024);
    }
}